// Round 14
// baseline (4597.071 us; speedup 1.0000x reference)
//
#include <hip/hip_runtime.h>
#include <hip/hip_bf16.h>
#include <hip/hip_fp16.h>

#define N_RES   4096
#define MAXD    4608
#define IN_DIM  1024
#define T_STEPS 128
#define B_SZ    128

typedef __attribute__((ext_vector_type(8))) short bf16x8;
typedef __attribute__((ext_vector_type(8))) _Float16 f16x8;
typedef __attribute__((ext_vector_type(4))) float f32x4;

__device__ __forceinline__ short f2bf(float x) {
  union { float f; unsigned u; } v; v.f = x;
  unsigned r = v.u + 0x7fffu + ((v.u >> 16) & 1u);
  return (short)(r >> 16);
}
__device__ __forceinline__ short f2h(float x) {
  union { _Float16 h; short s; } u; u.h = (_Float16)x; return u.s;
}
__device__ __forceinline__ float h2f(short s) {
  union { _Float16 h; short s; } u; u.s = s; return (float)u.h;
}
// float -> OCP e4m3 (RNE, satfinite) via v_cvt_pk_fp8_f32 (gfx950 = OCP)
__device__ __forceinline__ unsigned char f2fp8(float x) {
  return (unsigned char)(__builtin_amdgcn_cvt_pk_fp8_f32(x, 0.f, 0, false) & 0xff);
}

__device__ __forceinline__ void gload16(const void* g, void* l) {
  __builtin_amdgcn_global_load_lds(
      (const __attribute__((address_space(1))) void*)g,
      (__attribute__((address_space(3))) void*)l,
      16, 0, 0);
}

// ---------------- zero ONLY the padding columns [4096,4608) ----------------
__global__ void k_zero_pad(float* __restrict__ out) {
  int row = blockIdx.x;            // 16384 rows (T*B)
  int t = threadIdx.x;             // 128 threads * float4 = 512 cols
  *(float4*)(out + (size_t)row * MAXD + N_RES + t * 4) = float4{0.f, 0.f, 0.f, 0.f};
}

// ---------------- zero the 64 region counters ----------------
__global__ void k_zero_cnt(int* __restrict__ cnt) {
  cnt[threadIdx.x] = 0;
}

// ---------------- init state from state0 (fp32 + fp8) ----------------
__global__ void k_init_state(const float* __restrict__ s0,
                             float* __restrict__ sF, unsigned char* __restrict__ s8) {
  int i = blockIdx.x * 256 + threadIdx.x;   // 128*4096 total
  int m = i >> 12, n = i & 4095;
  float v = s0[m * MAXD + n];
  sF[i] = v;
  s8[i] = f2fp8(v);
}

// ---------------- transpose W_res -> fp8 [n][k] ----------------
__global__ void k_wres_t(const float* __restrict__ W, unsigned char* __restrict__ bt) {
  __shared__ float tile[64][65];
  int k0 = blockIdx.y * 64, n0 = blockIdx.x * 64;
  int tx = threadIdx.x & 63, ty = threadIdx.x >> 6;   // 256 thr
  #pragma unroll
  for (int r = 0; r < 64; r += 4)
    tile[r + ty][tx] = W[(long)(k0 + r + ty) * N_RES + n0 + tx];
  __syncthreads();
  #pragma unroll
  for (int r = 0; r < 64; r += 4)
    bt[(long)(n0 + r + ty) * N_RES + k0 + tx] = f2fp8(tile[tx][r + ty]);
}

// ---------------- build B2 = fp16 rows of [W_in;W_gate]  [16384][1024] ---------
__global__ void k_build_b2(const float* __restrict__ Win,
                           const float* __restrict__ Wg, short* __restrict__ B2) {
  int r = blockIdx.x;   // 16384 rows
  const float* src = (r < N_RES) ? (Win + (long)r * IN_DIM)
                                 : (Wg + (long)(r - N_RES) * IN_DIM);
  short* dst = B2 + (long)r * IN_DIM;
  for (int c = threadIdx.x; c < IN_DIM; c += 256)
    dst[c] = f2h(src[c]);
}

// ---------------- build A2 = fp16 x chunk  [Tc*128][1024] ----------------
__global__ void k_build_a2(const float* __restrict__ x, short* __restrict__ A2, int t0) {
  int r = blockIdx.x;   // Tc*128 rows
  const float* src = x + (long)(t0 * B_SZ + r) * IN_DIM;
  short* dst = A2 + (long)r * IN_DIM;
  for (int c = threadIdx.x; c < IN_DIM; c += 256)
    dst[c] = f2h(src[c]);
}

// ---------------- precompute GEMM: C = A2 @ B2^T  (256x256 8-phase, fp16 K=1024) --
// Frozen from R12. Gates stored u8 (x255), ip stored f16.
__global__ __launch_bounds__(512, 2) void k_gemm_pre(
    const short* __restrict__ A2, const short* __restrict__ B2,
    _Float16* __restrict__ ip, unsigned char* __restrict__ gates, int Mrows) {
  __shared__ short lA[2][2][128 * 64];
  __shared__ short lB[2][2][128 * 64];
  int tid = threadIdx.x, lane = tid & 63, wid = tid >> 6;
  int wr = wid >> 2, wc = wid & 3;

  int nwg = gridDim.x, orig = blockIdx.x;
  int mtiles = nwg >> 6;
  int mt, nt;
  if ((mtiles & 3) == 0) {
    int xcd = orig & 7, idx = orig >> 3;
    int w = idx & 31, sq = idx >> 5;
    nt = xcd * 8 + (w & 7);
    mt = sq * 4 + (w >> 3);
  } else {
    int qx = nwg >> 3, rx = nwg & 7, xcd = orig & 7;
    int wgid = (xcd < rx ? xcd * (qx + 1) : rx * (qx + 1) + (xcd - rx) * qx) + (orig >> 3);
    mt = wgid >> 6; nt = wgid & 63;
  }
  long m0 = (long)mt * 256, n0 = (long)nt * 256;
  long mclamp = Mrows - 1;

  int c0 = tid, c1 = 512 + tid;
  int r0 = c0 >> 3, r1 = c1 >> 3;
  int cc0 = ((c0 & 7) ^ (r0 & 7)) * 8, cc1 = ((c1 & 7) ^ (r1 & 7)) * 8;

  const short *pA00, *pA01, *pA10, *pA11, *pB00, *pB01, *pB10, *pB11;
  {
    long a00 = m0 + r0;       if (a00 > mclamp) a00 = mclamp;
    long a01 = m0 + r1;       if (a01 > mclamp) a01 = mclamp;
    long a10 = m0 + 128 + r0; if (a10 > mclamp) a10 = mclamp;
    long a11 = m0 + 128 + r1; if (a11 > mclamp) a11 = mclamp;
    pA00 = A2 + a00 * IN_DIM + cc0;  pA01 = A2 + a01 * IN_DIM + cc1;
    pA10 = A2 + a10 * IN_DIM + cc0;  pA11 = A2 + a11 * IN_DIM + cc1;
    pB00 = B2 + (n0 + r0) * IN_DIM + cc0;        pB01 = B2 + (n0 + r1) * IN_DIM + cc1;
    pB10 = B2 + (n0 + 128 + r0) * IN_DIM + cc0;  pB11 = B2 + (n0 + 128 + r1) * IN_DIM + cc1;
  }

  #define STG_A0(kt, b) { gload16(pA00 + (kt)*64, &lA[b][0][c0*8]); gload16(pA01 + (kt)*64, &lA[b][0][c1*8]); }
  #define STG_A1(kt, b) { gload16(pA10 + (kt)*64, &lA[b][1][c0*8]); gload16(pA11 + (kt)*64, &lA[b][1][c1*8]); }
  #define STG_B0(kt, b) { gload16(pB00 + (kt)*64, &lB[b][0][c0*8]); gload16(pB01 + (kt)*64, &lB[b][0][c1*8]); }
  #define STG_B1(kt, b) { gload16(pB10 + (kt)*64, &lB[b][1][c0*8]); gload16(pB11 + (kt)*64, &lB[b][1][c1*8]); }

  int lm = lane & 15;
  int colS0 = ((lane >> 4) * 8) ^ ((lane & 7) << 3);
  int colS1 = (32 + (lane >> 4) * 8) ^ ((lane & 7) << 3);
  int arow[4], brow[2];
  #pragma unroll
  for (int i = 0; i < 4; ++i) arow[i] = (wr * 64 + i * 16 + lm) * 64;
  #pragma unroll
  for (int j = 0; j < 2; ++j) brow[j] = (wc * 32 + j * 16 + lm) * 64;

  f16x8 aF[4][2], bFh[2][2][2];
  f32x4 acc[2][4][4] = {};

  #define RD_A(qm, b) { _Pragma("unroll") for (int i = 0; i < 4; ++i) {        \
      aF[i][0] = *(const f16x8*)&lA[b][qm][arow[i] + colS0];                   \
      aF[i][1] = *(const f16x8*)&lA[b][qm][arow[i] + colS1]; } }
  #define RD_B(h, b) { _Pragma("unroll") for (int j = 0; j < 2; ++j) {         \
      bFh[h][j][0] = *(const f16x8*)&lB[b][h][brow[j] + colS0];                \
      bFh[h][j][1] = *(const f16x8*)&lB[b][h][brow[j] + colS1]; } }
  #define MM(qm, qn) { __builtin_amdgcn_s_setprio(1);                          \
      _Pragma("unroll") for (int i = 0; i < 4; ++i)                            \
      _Pragma("unroll") for (int j = 0; j < 2; ++j) {                          \
        acc[qm][i][(qn)*2+j] = __builtin_amdgcn_mfma_f32_16x16x32_f16(         \
            aF[i][0], bFh[qn][j][0], acc[qm][i][(qn)*2+j], 0, 0, 0);           \
        acc[qm][i][(qn)*2+j] = __builtin_amdgcn_mfma_f32_16x16x32_f16(         \
            aF[i][1], bFh[qn][j][1], acc[qm][i][(qn)*2+j], 0, 0, 0); }         \
      __builtin_amdgcn_s_setprio(0); }

  STG_A0(0, 0); STG_B0(0, 0); STG_B1(0, 0); STG_A1(0, 0);

  const int nk = IN_DIM / 64;   // 16
  for (int kt = 0; kt < nk; ++kt) {
    int buf = kt & 1, nbuf = buf ^ 1;
    int ktn = (kt + 1 < nk) ? kt + 1 : kt;
    asm volatile("s_waitcnt vmcnt(4)\n\ts_barrier" ::: "memory");
    RD_A(0, buf); RD_B(0, buf);
    STG_A0(ktn, nbuf);
    MM(0, 0);
    asm volatile("s_barrier" ::: "memory");
    asm volatile("s_waitcnt vmcnt(4)\n\ts_barrier" ::: "memory");
    RD_B(1, buf);
    STG_B0(ktn, nbuf);
    MM(0, 1);
    asm volatile("s_barrier" ::: "memory");
    asm volatile("s_waitcnt vmcnt(4)\n\ts_barrier" ::: "memory");
    RD_A(1, buf);
    STG_B1(ktn, nbuf);
    MM(1, 0);
    asm volatile("s_barrier" ::: "memory");
    STG_A1(ktn, nbuf);
    MM(1, 1);
    asm volatile("s_barrier" ::: "memory");
  }
  #undef STG_A0
  #undef STG_A1
  #undef STG_B0
  #undef STG_B1
  #undef RD_A
  #undef RD_B
  #undef MM

  #pragma unroll
  for (int qm = 0; qm < 2; ++qm)
    #pragma unroll
    for (int i = 0; i < 4; ++i)
      #pragma unroll
      for (int qn = 0; qn < 2; ++qn)
        #pragma unroll
        for (int j = 0; j < 2; ++j)
          #pragma unroll
          for (int q = 0; q < 4; ++q) {
            long m = m0 + qm * 128 + wr * 64 + i * 16 + (lane >> 4) * 4 + q;
            long n = n0 + qn * 128 + wc * 32 + j * 16 + lm;
            if (m >= Mrows) continue;
            float v = acc[qm][i][qn * 2 + j][q];
            if (n < N_RES) {
              ip[m * N_RES + n] = (_Float16)v;
            } else {
              float g = 1.f / (1.f + __expf(-v));
              gates[m * 12288 + (n - N_RES)] = (unsigned char)(g * 255.f + 0.5f);
            }
          }
}

// ---------------- FUSED per-step: K-split fp8 GEMM + last-finisher reduce ------
// 256 blocks = 2 m_h x 4 kc x 32 n_t (all 4 kc-blocks of a region on ONE XCD).
// After partial store, atomicAdd on cnt[region]; the 4th finisher reduces the
// 64x128 region (partials L2-local) and applies the gate epilogue.
__global__ __launch_bounds__(512) void k_step_fused(
    const unsigned char* __restrict__ A8,  // state fp8 (read buf) [128][4096]
    const unsigned char* __restrict__ B8,  // Wres^T fp8 [4096][4096]
    short* __restrict__ part,              // [4][128][4096] f16
    const _Float16* __restrict__ ip,       // [128][4096]
    const unsigned char* __restrict__ gt,  // [128][12288] u8
    float* __restrict__ sF,                // fp32 state
    unsigned char* __restrict__ s8w,       // fp8 state (write buf)
    float* __restrict__ out,               // d_out + t*128*4608
    int* __restrict__ cnt) {               // [64] region counters
  __shared__ unsigned char lA[3][64 * 256];    // 3 x 16 KiB
  __shared__ unsigned char lB[3][128 * 256];   // 3 x 32 KiB (total 144 KiB)
  __shared__ int sDone;
  int tid = threadIdx.x, lane = tid & 63, wid = tid >> 6;   // 8 waves
  int wm = wid >> 2, wn = wid & 3;      // wave tile 32x32 (2m x 4n waves)

  int b = blockIdx.x;
  int xcd = b & 7, i2 = b >> 3;
  int m_h = i2 & 1, kc = (i2 >> 1) & 3, n_tl = i2 >> 3;   // 0..3
  int n_t = xcd * 4 + n_tl;             // 0..31
  int m0 = m_h * 64, n0 = n_t * 128, kb = kc * 1024;      // kb in elems
  int region = m_h * 32 + n_t;          // 0..63

  const unsigned char* pA[2];
  const unsigned char* pB[4];
  #pragma unroll
  for (int i = 0; i < 2; ++i) {
    int c = i * 512 + tid, row = c >> 4;
    pA[i] = A8 + (size_t)(m0 + row) * N_RES + kb + (((c & 15) ^ (row & 7)) * 16);
  }
  #pragma unroll
  for (int i = 0; i < 4; ++i) {
    int c = i * 512 + tid, row = c >> 4;
    pB[i] = B8 + (size_t)(n0 + row) * N_RES + kb + (((c & 15) ^ (row & 7)) * 16);
  }

  #define STAGE(kt, bi) { int k0s = (kt) * 256;                                \
    _Pragma("unroll") for (int i = 0; i < 2; ++i)                              \
      gload16(pA[i] + k0s, &lA[bi][(i * 512 + tid) * 16]);                     \
    _Pragma("unroll") for (int i = 0; i < 4; ++i)                              \
      gload16(pB[i] + k0s, &lB[bi][(i * 512 + tid) * 16]); }

  f32x4 acc[2][2] = {};

  #define COMPUTE(bi)                                                          \
    { _Pragma("unroll")                                                        \
      for (int kk = 0; kk < 256; kk += 32) {                                   \
        int colS = (kk + (lane >> 4) * 8) ^ ((lane & 7) << 4);                 \
        long aF0 = *(const long*)&lA[bi][(wm * 32 + (lane & 15)) * 256 + colS];      \
        long aF1 = *(const long*)&lA[bi][(wm * 32 + 16 + (lane & 15)) * 256 + colS]; \
        long bF0 = *(const long*)&lB[bi][(wn * 32 + (lane & 15)) * 256 + colS];      \
        long bF1 = *(const long*)&lB[bi][(wn * 32 + 16 + (lane & 15)) * 256 + colS]; \
        acc[0][0] = __builtin_amdgcn_mfma_f32_16x16x32_fp8_fp8(aF0, bF0, acc[0][0], 0, 0, 0); \
        acc[0][1] = __builtin_amdgcn_mfma_f32_16x16x32_fp8_fp8(aF0, bF1, acc[0][1], 0, 0, 0); \
        acc[1][0] = __builtin_amdgcn_mfma_f32_16x16x32_fp8_fp8(aF1, bF0, acc[1][0], 0, 0, 0); \
        acc[1][1] = __builtin_amdgcn_mfma_f32_16x16x32_fp8_fp8(aF1, bF1, acc[1][1], 0, 0, 0); \
      } }

  STAGE(0, 0);
  STAGE(1, 1);                          // 12 loads in flight

  int bi = 0, sb = 2;
  for (int kt = 0; kt < 3; ++kt) {      // tiles 0..2; tile 3 in tail
    asm volatile("s_waitcnt vmcnt(6)" ::: "memory");
    __builtin_amdgcn_s_barrier();
    if (kt < 2) STAGE(kt + 2, sb);
    COMPUTE(bi);
    ++bi; if (bi == 3) bi = 0;
    ++sb; if (sb == 3) sb = 0;
  }
  asm volatile("s_waitcnt vmcnt(0)" ::: "memory");
  __builtin_amdgcn_s_barrier();
  COMPUTE(bi);                          // tile 3 (bi == 0)
  #undef STAGE
  #undef COMPUTE

  short* dst = part + (size_t)kc * (B_SZ * N_RES);
  #pragma unroll
  for (int i = 0; i < 2; ++i)
    #pragma unroll
    for (int j = 0; j < 2; ++j)
      #pragma unroll
      for (int q = 0; q < 4; ++q) {
        int m = m0 + wm * 32 + i * 16 + (lane >> 4) * 4 + q;
        int n = n0 + wn * 32 + j * 16 + (lane & 15);
        dst[(size_t)m * N_RES + n] = f2h(acc[i][j][q]);
      }

  // ---- completion handshake (all 4 kc-blocks of this region share one XCD) ----
  __syncthreads();                      // drains vmcnt: partial stores complete
  if (tid == 0) {
    __threadfence();                    // release: partials visible device-wide
    int prev = atomicAdd(&cnt[region], 1);
    sDone = (prev == 3);
    if (prev == 3) cnt[region] = 0;     // safe: all 4 increments already done
  }
  __syncthreads();
  if (!sDone) return;

  // ---- last finisher: reduce 64x128 region + gate epilogue ----
  __threadfence();                      // acquire: see other blocks' partials
  const float is = 1.f / 255.f;
  #pragma unroll
  for (int v = 0; v < 4; ++v) {
    int slot = v * 512 + tid;           // 0..2047 (64 rows x 32 float4-cols)
    int mloc = slot >> 5;
    int nloc = (slot & 31) * 4;
    int m = m0 + mloc;                  // m0 == m_h*64 (region rows)
    int n = n0 + nloc;
    size_t e = (size_t)m * N_RES + n;

    float res[4] = {0.f, 0.f, 0.f, 0.f};
    #pragma unroll
    for (int k2 = 0; k2 < 4; ++k2) {
      short4 p = *(const short4*)(part + ((size_t)k2 << 19) + e);
      res[0] += h2f(p.x); res[1] += h2f(p.y); res[2] += h2f(p.z); res[3] += h2f(p.w);
    }
    short4 ipr = *(const short4*)((const short*)ip + e);
    const unsigned char* g = gt + (size_t)m * 12288 + n;
    uchar4 igr = *(const uchar4*)g;
    uchar4 fgr = *(const uchar4*)(g + 4096);
    uchar4 ogr = *(const uchar4*)(g + 8192);
    float4 pr = *(const float4*)(sF + e);

    float prv[4] = { pr.x, pr.y, pr.z, pr.w };
    short ipa[4] = { ipr.x, ipr.y, ipr.z, ipr.w };
    unsigned char iga[4] = { igr.x, igr.y, igr.z, igr.w };
    unsigned char fga[4] = { fgr.x, fgr.y, fgr.z, fgr.w };
    unsigned char oga[4] = { ogr.x, ogr.y, ogr.z, ogr.w };

    float so[4];
    unsigned char s8[4];
    #pragma unroll
    for (int q = 0; q < 4; ++q) {
      float s = 0.9f * ((float)fga[q] * is * prv[q])
              + 0.1f * tanhf((float)iga[q] * is * (h2f(ipa[q]) + res[q]));
      s = (float)oga[q] * is * s;
      if (s > 0.5f) s -= 0.5f;
      so[q] = s;
      s8[q] = f2fp8(s);
    }
    *(float4*)(out + (size_t)m * MAXD + n) = float4{so[0], so[1], so[2], so[3]};
    *(float4*)(sF + e) = float4{so[0], so[1], so[2], so[3]};
    *(uchar4*)(s8w + e) = uchar4{s8[0], s8[1], s8[2], s8[3]};
  }
}

extern "C" void kernel_launch(void* const* d_in, const int* in_sizes, int n_in,
                              void* d_out, int out_size, void* d_ws, size_t ws_size,
                              hipStream_t stream) {
  const float* x      = (const float*)d_in[0];
  const float* state0 = (const float*)d_in[1];
  const float* W_res  = (const float*)d_in[2];
  const float* W_in   = (const float*)d_in[3];
  const float* W_gate = (const float*)d_in[4];
  float* out = (float*)d_out;
  char* ws = (char*)d_ws;

  size_t off = 0;
  unsigned char* WresBT8 = (unsigned char*)(ws + off); off += (size_t)N_RES * N_RES;  // 16.8 MB
  short* B2     = (short*)(ws + off); off += (size_t)16384 * IN_DIM * 2;      // 33.6 MB
  float* sF     = (float*)(ws + off); off += (size_t)B_SZ * N_RES * 4;        // 2 MB
  unsigned char* s8_0 = (unsigned char*)(ws + off); off += (size_t)B_SZ * N_RES;  // 0.5 MB
  unsigned char* s8_1 = (unsigned char*)(ws + off); off += (size_t)B_SZ * N_RES;  // 0.5 MB
  short* part   = (short*)(ws + off); off += (size_t)4 * B_SZ * N_RES * 2;    // 4 MB
  int*   cnt    = (int*)(ws + off);   off += 64 * sizeof(int);
  off = (off + 255) & ~(size_t)255;
  size_t fixed = off;
  size_t per = (size_t)B_SZ * IN_DIM * 2 + (size_t)B_SZ * N_RES * 2 + (size_t)B_SZ * 12288;

  int Tc = T_STEPS;
  while (Tc > 1 && fixed + (size_t)Tc * per > ws_size) Tc >>= 1;

  short*          A2  = (short*)(ws + fixed);
  _Float16*       ipb = (_Float16*)(ws + fixed + (size_t)Tc * B_SZ * IN_DIM * 2);
  unsigned char*  gtb = (unsigned char*)(ws + fixed + (size_t)Tc * B_SZ * IN_DIM * 2
                                         + (size_t)Tc * B_SZ * N_RES * 2);

  k_zero_pad<<<T_STEPS * B_SZ, 128, 0, stream>>>(out);
  k_zero_cnt<<<1, 64, 0, stream>>>(cnt);
  k_init_state<<<(B_SZ * N_RES) / 256, 256, 0, stream>>>(state0, sF, s8_0);
  k_wres_t<<<dim3(64, 64), 256, 0, stream>>>(W_res, WresBT8);
  k_build_b2<<<16384, 256, 0, stream>>>(W_in, W_gate, B2);

  for (int t0 = 0; t0 < T_STEPS; t0 += Tc) {
    k_build_a2<<<Tc * B_SZ, 256, 0, stream>>>(x, A2, t0);
    int Mrows = Tc * B_SZ;
    int mtiles = (Mrows + 255) / 256;
    k_gemm_pre<<<mtiles * 64, 512, 0, stream>>>(A2, B2, ipb, gtb, Mrows);
    for (int tl = 0; tl < Tc; ++tl) {
      int t = t0 + tl;
      const unsigned char* Ar = (t & 1) ? s8_1 : s8_0;
      unsigned char*       Aw = (t & 1) ? s8_0 : s8_1;
      k_step_fused<<<256, 512, 0, stream>>>(
          Ar, WresBT8, part,
          ipb + (size_t)tl * B_SZ * N_RES,
          gtb + (size_t)tl * B_SZ * 12288,
          sF, Aw,
          out + (size_t)t * B_SZ * MAXD,
          cnt);
    }
  }
}

// Round 16
// 2422.282 us; speedup vs baseline: 1.8978x; 1.8978x over previous
//
#include <hip/hip_runtime.h>
#include <hip/hip_bf16.h>
#include <hip/hip_fp16.h>

#define N_RES   4096
#define MAXD    4608
#define IN_DIM  1024
#define T_STEPS 128
#define B_SZ    128

typedef __attribute__((ext_vector_type(8))) short bf16x8;
typedef __attribute__((ext_vector_type(8))) _Float16 f16x8;
typedef __attribute__((ext_vector_type(4))) float f32x4;

__device__ __forceinline__ short f2bf(float x) {
  union { float f; unsigned u; } v; v.f = x;
  unsigned r = v.u + 0x7fffu + ((v.u >> 16) & 1u);
  return (short)(r >> 16);
}
__device__ __forceinline__ short f2h(float x) {
  union { _Float16 h; short s; } u; u.h = (_Float16)x; return u.s;
}
__device__ __forceinline__ float h2f(short s) {
  union { _Float16 h; short s; } u; u.s = s; return (float)u.h;
}
// float -> OCP e4m3 (RNE, satfinite) via v_cvt_pk_fp8_f32 (gfx950 = OCP)
__device__ __forceinline__ unsigned char f2fp8(float x) {
  return (unsigned char)(__builtin_amdgcn_cvt_pk_fp8_f32(x, 0.f, 0, false) & 0xff);
}

__device__ __forceinline__ void gload16(const void* g, void* l) {
  __builtin_amdgcn_global_load_lds(
      (const __attribute__((address_space(1))) void*)g,
      (__attribute__((address_space(3))) void*)l,
      16, 0, 0);
}

// ---------------- zero ONLY the padding columns [4096,4608) ----------------
__global__ void k_zero_pad(float* __restrict__ out) {
  int row = blockIdx.x;            // 16384 rows (T*B)
  int t = threadIdx.x;             // 128 threads * float4 = 512 cols
  *(float4*)(out + (size_t)row * MAXD + N_RES + t * 4) = float4{0.f, 0.f, 0.f, 0.f};
}

// ---------------- init state from state0 (fp32 + fp8) ----------------
__global__ void k_init_state(const float* __restrict__ s0,
                             float* __restrict__ sF, unsigned char* __restrict__ s8) {
  int i = blockIdx.x * 256 + threadIdx.x;   // 128*4096 total
  int m = i >> 12, n = i & 4095;
  float v = s0[m * MAXD + n];
  sF[i] = v;
  s8[i] = f2fp8(v);
}

// ---------------- transpose W_res -> fp8 [n][k] ----------------
__global__ void k_wres_t(const float* __restrict__ W, unsigned char* __restrict__ bt) {
  __shared__ float tile[64][65];
  int k0 = blockIdx.y * 64, n0 = blockIdx.x * 64;
  int tx = threadIdx.x & 63, ty = threadIdx.x >> 6;   // 256 thr
  #pragma unroll
  for (int r = 0; r < 64; r += 4)
    tile[r + ty][tx] = W[(long)(k0 + r + ty) * N_RES + n0 + tx];
  __syncthreads();
  #pragma unroll
  for (int r = 0; r < 64; r += 4)
    bt[(long)(n0 + r + ty) * N_RES + k0 + tx] = f2fp8(tile[tx][r + ty]);
}

// ---------------- build B2 = fp16 rows of [W_in;W_gate]  [16384][1024] ---------
__global__ void k_build_b2(const float* __restrict__ Win,
                           const float* __restrict__ Wg, short* __restrict__ B2) {
  int r = blockIdx.x;   // 16384 rows
  const float* src = (r < N_RES) ? (Win + (long)r * IN_DIM)
                                 : (Wg + (long)(r - N_RES) * IN_DIM);
  short* dst = B2 + (long)r * IN_DIM;
  for (int c = threadIdx.x; c < IN_DIM; c += 256)
    dst[c] = f2h(src[c]);
}

// ---------------- build A2 = fp16 x chunk  [Tc*128][1024] ----------------
__global__ void k_build_a2(const float* __restrict__ x, short* __restrict__ A2, int t0) {
  int r = blockIdx.x;   // Tc*128 rows
  const float* src = x + (long)(t0 * B_SZ + r) * IN_DIM;
  short* dst = A2 + (long)r * IN_DIM;
  for (int c = threadIdx.x; c < IN_DIM; c += 256)
    dst[c] = f2h(src[c]);
}

// ---------------- precompute GEMM: C = A2 @ B2^T  (256x256 8-phase, fp16 K=1024) --
// Frozen from R12. Gates stored u8 (x255), ip stored f16.
__global__ __launch_bounds__(512, 2) void k_gemm_pre(
    const short* __restrict__ A2, const short* __restrict__ B2,
    _Float16* __restrict__ ip, unsigned char* __restrict__ gates, int Mrows) {
  __shared__ short lA[2][2][128 * 64];
  __shared__ short lB[2][2][128 * 64];
  int tid = threadIdx.x, lane = tid & 63, wid = tid >> 6;
  int wr = wid >> 2, wc = wid & 3;

  int nwg = gridDim.x, orig = blockIdx.x;
  int mtiles = nwg >> 6;
  int mt, nt;
  if ((mtiles & 3) == 0) {
    int xcd = orig & 7, idx = orig >> 3;
    int w = idx & 31, sq = idx >> 5;
    nt = xcd * 8 + (w & 7);
    mt = sq * 4 + (w >> 3);
  } else {
    int qx = nwg >> 3, rx = nwg & 7, xcd = orig & 7;
    int wgid = (xcd < rx ? xcd * (qx + 1) : rx * (qx + 1) + (xcd - rx) * qx) + (orig >> 3);
    mt = wgid >> 6; nt = wgid & 63;
  }
  long m0 = (long)mt * 256, n0 = (long)nt * 256;
  long mclamp = Mrows - 1;

  int c0 = tid, c1 = 512 + tid;
  int r0 = c0 >> 3, r1 = c1 >> 3;
  int cc0 = ((c0 & 7) ^ (r0 & 7)) * 8, cc1 = ((c1 & 7) ^ (r1 & 7)) * 8;

  const short *pA00, *pA01, *pA10, *pA11, *pB00, *pB01, *pB10, *pB11;
  {
    long a00 = m0 + r0;       if (a00 > mclamp) a00 = mclamp;
    long a01 = m0 + r1;       if (a01 > mclamp) a01 = mclamp;
    long a10 = m0 + 128 + r0; if (a10 > mclamp) a10 = mclamp;
    long a11 = m0 + 128 + r1; if (a11 > mclamp) a11 = mclamp;
    pA00 = A2 + a00 * IN_DIM + cc0;  pA01 = A2 + a01 * IN_DIM + cc1;
    pA10 = A2 + a10 * IN_DIM + cc0;  pA11 = A2 + a11 * IN_DIM + cc1;
    pB00 = B2 + (n0 + r0) * IN_DIM + cc0;        pB01 = B2 + (n0 + r1) * IN_DIM + cc1;
    pB10 = B2 + (n0 + 128 + r0) * IN_DIM + cc0;  pB11 = B2 + (n0 + 128 + r1) * IN_DIM + cc1;
  }

  #define STG_A0(kt, b) { gload16(pA00 + (kt)*64, &lA[b][0][c0*8]); gload16(pA01 + (kt)*64, &lA[b][0][c1*8]); }
  #define STG_A1(kt, b) { gload16(pA10 + (kt)*64, &lA[b][1][c0*8]); gload16(pA11 + (kt)*64, &lA[b][1][c1*8]); }
  #define STG_B0(kt, b) { gload16(pB00 + (kt)*64, &lB[b][0][c0*8]); gload16(pB01 + (kt)*64, &lB[b][0][c1*8]); }
  #define STG_B1(kt, b) { gload16(pB10 + (kt)*64, &lB[b][1][c0*8]); gload16(pB11 + (kt)*64, &lB[b][1][c1*8]); }

  int lm = lane & 15;
  int colS0 = ((lane >> 4) * 8) ^ ((lane & 7) << 3);
  int colS1 = (32 + (lane >> 4) * 8) ^ ((lane & 7) << 3);
  int arow[4], brow[2];
  #pragma unroll
  for (int i = 0; i < 4; ++i) arow[i] = (wr * 64 + i * 16 + lm) * 64;
  #pragma unroll
  for (int j = 0; j < 2; ++j) brow[j] = (wc * 32 + j * 16 + lm) * 64;

  f16x8 aF[4][2], bFh[2][2][2];
  f32x4 acc[2][4][4] = {};

  #define RD_A(qm, b) { _Pragma("unroll") for (int i = 0; i < 4; ++i) {        \
      aF[i][0] = *(const f16x8*)&lA[b][qm][arow[i] + colS0];                   \
      aF[i][1] = *(const f16x8*)&lA[b][qm][arow[i] + colS1]; } }
  #define RD_B(h, b) { _Pragma("unroll") for (int j = 0; j < 2; ++j) {         \
      bFh[h][j][0] = *(const f16x8*)&lB[b][h][brow[j] + colS0];                \
      bFh[h][j][1] = *(const f16x8*)&lB[b][h][brow[j] + colS1]; } }
  #define MM(qm, qn) { __builtin_amdgcn_s_setprio(1);                          \
      _Pragma("unroll") for (int i = 0; i < 4; ++i)                            \
      _Pragma("unroll") for (int j = 0; j < 2; ++j) {                          \
        acc[qm][i][(qn)*2+j] = __builtin_amdgcn_mfma_f32_16x16x32_f16(         \
            aF[i][0], bFh[qn][j][0], acc[qm][i][(qn)*2+j], 0, 0, 0);           \
        acc[qm][i][(qn)*2+j] = __builtin_amdgcn_mfma_f32_16x16x32_f16(         \
            aF[i][1], bFh[qn][j][1], acc[qm][i][(qn)*2+j], 0, 0, 0); }         \
      __builtin_amdgcn_s_setprio(0); }

  STG_A0(0, 0); STG_B0(0, 0); STG_B1(0, 0); STG_A1(0, 0);

  const int nk = IN_DIM / 64;   // 16
  for (int kt = 0; kt < nk; ++kt) {
    int buf = kt & 1, nbuf = buf ^ 1;
    int ktn = (kt + 1 < nk) ? kt + 1 : kt;
    asm volatile("s_waitcnt vmcnt(4)\n\ts_barrier" ::: "memory");
    RD_A(0, buf); RD_B(0, buf);
    STG_A0(ktn, nbuf);
    MM(0, 0);
    asm volatile("s_barrier" ::: "memory");
    asm volatile("s_waitcnt vmcnt(4)\n\ts_barrier" ::: "memory");
    RD_B(1, buf);
    STG_B0(ktn, nbuf);
    MM(0, 1);
    asm volatile("s_barrier" ::: "memory");
    asm volatile("s_waitcnt vmcnt(4)\n\ts_barrier" ::: "memory");
    RD_A(1, buf);
    STG_B1(ktn, nbuf);
    MM(1, 0);
    asm volatile("s_barrier" ::: "memory");
    STG_A1(ktn, nbuf);
    MM(1, 1);
    asm volatile("s_barrier" ::: "memory");
  }
  #undef STG_A0
  #undef STG_A1
  #undef STG_B0
  #undef STG_B1
  #undef RD_A
  #undef RD_B
  #undef MM

  #pragma unroll
  for (int qm = 0; qm < 2; ++qm)
    #pragma unroll
    for (int i = 0; i < 4; ++i)
      #pragma unroll
      for (int qn = 0; qn < 2; ++qn)
        #pragma unroll
        for (int j = 0; j < 2; ++j)
          #pragma unroll
          for (int q = 0; q < 4; ++q) {
            long m = m0 + qm * 128 + wr * 64 + i * 16 + (lane >> 4) * 4 + q;
            long n = n0 + qn * 128 + wc * 32 + j * 16 + lm;
            if (m >= Mrows) continue;
            float v = acc[qm][i][qn * 2 + j][q];
            if (n < N_RES) {
              ip[m * N_RES + n] = (_Float16)v;
            } else {
              float g = 1.f / (1.f + __expf(-v));
              gates[m * 12288 + (n - N_RES)] = (unsigned char)(g * 255.f + 0.5f);
            }
          }
}

// ---------------- per-step GEMM (K-split, fp8 operands) ----------------
// 256 blocks = 2 m_h x 4 kc x 32 n_t. BM=64, BN=128, Kc=1024 fp8 elems,
// BK=256 elems = 256 B/row. 4 K-tiles, 3-buffer depth-2 counted pipeline
// (vmcnt(6)). Partials f16. PROVEN in R13 — do not modify.
__global__ __launch_bounds__(512) void k_step_gemm(
    const unsigned char* __restrict__ A8,  // state fp8 (read buf) [128][4096]
    const unsigned char* __restrict__ B8,  // Wres^T fp8 [4096][4096]
    short* __restrict__ part) {            // [4][128][4096] f16
  __shared__ unsigned char lA[3][64 * 256];    // 3 x 16 KiB
  __shared__ unsigned char lB[3][128 * 256];   // 3 x 32 KiB (total 144 KiB)
  int tid = threadIdx.x, lane = tid & 63, wid = tid >> 6;   // 8 waves
  int wm = wid >> 2, wn = wid & 3;      // wave tile 32x32 (2m x 4n waves)

  int b = blockIdx.x;
  int xcd = b & 7, i2 = b >> 3;
  int m_h = i2 & 1, kc = (i2 >> 1) & 3, n_tl = i2 >> 3;   // 0..3
  int n_t = xcd * 4 + n_tl;             // 0..31
  int m0 = m_h * 64, n0 = n_t * 128, kb = kc * 1024;      // kb in elems

  // staging: A 64x256B = 1024 16B-chunks (2/thr), B 128x256B = 2048 (4/thr)
  // chunk c: row=c>>4, colchunk=(c&15)^(row&7); dest linear c*16B.
  const unsigned char* pA[2];
  const unsigned char* pB[4];
  #pragma unroll
  for (int i = 0; i < 2; ++i) {
    int c = i * 512 + tid, row = c >> 4;
    pA[i] = A8 + (size_t)(m0 + row) * N_RES + kb + (((c & 15) ^ (row & 7)) * 16);
  }
  #pragma unroll
  for (int i = 0; i < 4; ++i) {
    int c = i * 512 + tid, row = c >> 4;
    pB[i] = B8 + (size_t)(n0 + row) * N_RES + kb + (((c & 15) ^ (row & 7)) * 16);
  }

  #define STAGE(kt, bi) { int k0s = (kt) * 256;                                \
    _Pragma("unroll") for (int i = 0; i < 2; ++i)                              \
      gload16(pA[i] + k0s, &lA[bi][(i * 512 + tid) * 16]);                     \
    _Pragma("unroll") for (int i = 0; i < 4; ++i)                              \
      gload16(pB[i] + k0s, &lB[bi][(i * 512 + tid) * 16]); }

  f32x4 acc[2][2] = {};

  // fragment: lane holds 8 consecutive fp8 at k = (lane>>4)*8 (+kk), row = base+(lane&15)
  // swizzled byte col: b ^ ((lane&7)<<4)  (row&7 == lane&7 for all our rows)
  #define COMPUTE(bi)                                                          \
    { _Pragma("unroll")                                                        \
      for (int kk = 0; kk < 256; kk += 32) {                                   \
        int colS = (kk + (lane >> 4) * 8) ^ ((lane & 7) << 4);                 \
        long aF0 = *(const long*)&lA[bi][(wm * 32 + (lane & 15)) * 256 + colS];      \
        long aF1 = *(const long*)&lA[bi][(wm * 32 + 16 + (lane & 15)) * 256 + colS]; \
        long bF0 = *(const long*)&lB[bi][(wn * 32 + (lane & 15)) * 256 + colS];      \
        long bF1 = *(const long*)&lB[bi][(wn * 32 + 16 + (lane & 15)) * 256 + colS]; \
        acc[0][0] = __builtin_amdgcn_mfma_f32_16x16x32_fp8_fp8(aF0, bF0, acc[0][0], 0, 0, 0); \
        acc[0][1] = __builtin_amdgcn_mfma_f32_16x16x32_fp8_fp8(aF0, bF1, acc[0][1], 0, 0, 0); \
        acc[1][0] = __builtin_amdgcn_mfma_f32_16x16x32_fp8_fp8(aF1, bF0, acc[1][0], 0, 0, 0); \
        acc[1][1] = __builtin_amdgcn_mfma_f32_16x16x32_fp8_fp8(aF1, bF1, acc[1][1], 0, 0, 0); \
      } }

  STAGE(0, 0);
  STAGE(1, 1);                          // 12 loads in flight

  int bi = 0, sb = 2;
  for (int kt = 0; kt < 3; ++kt) {      // tiles 0..2; tile 3 in tail
    asm volatile("s_waitcnt vmcnt(6)" ::: "memory");
    __builtin_amdgcn_s_barrier();
    if (kt < 2) STAGE(kt + 2, sb);
    COMPUTE(bi);
    ++bi; if (bi == 3) bi = 0;
    ++sb; if (sb == 3) sb = 0;
  }
  asm volatile("s_waitcnt vmcnt(0)" ::: "memory");
  __builtin_amdgcn_s_barrier();
  COMPUTE(bi);                          // tile 3 (bi == 0)
  #undef STAGE
  #undef COMPUTE

  short* dst = part + (size_t)kc * (B_SZ * N_RES);
  #pragma unroll
  for (int i = 0; i < 2; ++i)
    #pragma unroll
    for (int j = 0; j < 2; ++j)
      #pragma unroll
      for (int q = 0; q < 4; ++q) {
        int m = m0 + wm * 32 + i * 16 + (lane >> 4) * 4 + q;
        int n = n0 + wn * 32 + j * 16 + (lane & 15);
        dst[(size_t)m * N_RES + n] = f2h(acc[i][j][q]);
      }
}

// ---------------- per-step reduce + gate epilogue ----------------
// 512 blocks x 256 thr, 4 elems/thread. Sums 4 fp16 K-partials, applies u8
// gates / tanh / spike, writes out + fp32 state + fp8 state.
__global__ void k_step_red(
    const short* __restrict__ part,     // [4][128][4096] f16
    const _Float16* __restrict__ ip,    // [128][4096]
    const unsigned char* __restrict__ gt, // [128][12288] u8
    float* __restrict__ sF,             // fp32 state
    unsigned char* __restrict__ s8w,    // fp8 state (write buf)
    float* __restrict__ out) {          // d_out + t*128*4608
  int e = (blockIdx.x * 256 + threadIdx.x) * 4;
  int m = e >> 12, n = e & 4095;
  float res[4] = {0.f, 0.f, 0.f, 0.f};
  #pragma unroll
  for (int k = 0; k < 4; ++k) {
    short4 p = *(const short4*)(part + ((size_t)k << 19) + e);
    res[0] += h2f(p.x); res[1] += h2f(p.y); res[2] += h2f(p.z); res[3] += h2f(p.w);
  }
  short4 ipr = *(const short4*)((const short*)ip + e);
  const unsigned char* g = gt + (size_t)m * 12288 + n;
  uchar4 igr = *(const uchar4*)g;
  uchar4 fgr = *(const uchar4*)(g + 4096);
  uchar4 ogr = *(const uchar4*)(g + 8192);
  float4 pr = *(const float4*)(sF + e);

  float prv[4] = { pr.x, pr.y, pr.z, pr.w };
  short ipa[4] = { ipr.x, ipr.y, ipr.z, ipr.w };
  unsigned char iga[4] = { igr.x, igr.y, igr.z, igr.w };
  unsigned char fga[4] = { fgr.x, fgr.y, fgr.z, fgr.w };
  unsigned char oga[4] = { ogr.x, ogr.y, ogr.z, ogr.w };

  const float is = 1.f / 255.f;
  float so[4];
  unsigned char s8[4];
  #pragma unroll
  for (int q = 0; q < 4; ++q) {
    float s = 0.9f * ((float)fga[q] * is * prv[q])
            + 0.1f * tanhf((float)iga[q] * is * (h2f(ipa[q]) + res[q]));
    s = (float)oga[q] * is * s;
    if (s > 0.5f) s -= 0.5f;
    so[q] = s;
    s8[q] = f2fp8(s);
  }
  *(float4*)(out + (size_t)m * MAXD + n) = float4{so[0], so[1], so[2], so[3]};
  *(float4*)(sF + e) = float4{so[0], so[1], so[2], so[3]};
  *(uchar4*)(s8w + e) = uchar4{s8[0], s8[1], s8[2], s8[3]};
}

extern "C" void kernel_launch(void* const* d_in, const int* in_sizes, int n_in,
                              void* d_out, int out_size, void* d_ws, size_t ws_size,
                              hipStream_t stream) {
  const float* x      = (const float*)d_in[0];
  const float* state0 = (const float*)d_in[1];
  const float* W_res  = (const float*)d_in[2];
  const float* W_in   = (const float*)d_in[3];
  const float* W_gate = (const float*)d_in[4];
  float* out = (float*)d_out;
  char* ws = (char*)d_ws;

  size_t off = 0;
  unsigned char* WresBT8 = (unsigned char*)(ws + off); off += (size_t)N_RES * N_RES;  // 16.8 MB
  short* B2     = (short*)(ws + off); off += (size_t)16384 * IN_DIM * 2;      // 33.6 MB
  float* sF     = (float*)(ws + off); off += (size_t)B_SZ * N_RES * 4;        // 2 MB
  unsigned char* s8_0 = (unsigned char*)(ws + off); off += (size_t)B_SZ * N_RES;  // 0.5 MB
  unsigned char* s8_1 = (unsigned char*)(ws + off); off += (size_t)B_SZ * N_RES;  // 0.5 MB
  short* part   = (short*)(ws + off); off += (size_t)4 * B_SZ * N_RES * 2;    // 4 MB
  size_t fixed = off;
  size_t per = (size_t)B_SZ * IN_DIM * 2 + (size_t)B_SZ * N_RES * 2 + (size_t)B_SZ * 12288;

  int Tc = T_STEPS;
  while (Tc > 1 && fixed + (size_t)Tc * per > ws_size) Tc >>= 1;

  short*          A2  = (short*)(ws + fixed);
  _Float16*       ipb = (_Float16*)(ws + fixed + (size_t)Tc * B_SZ * IN_DIM * 2);
  unsigned char*  gtb = (unsigned char*)(ws + fixed + (size_t)Tc * B_SZ * IN_DIM * 2
                                         + (size_t)Tc * B_SZ * N_RES * 2);

  k_zero_pad<<<T_STEPS * B_SZ, 128, 0, stream>>>(out);
  k_init_state<<<(B_SZ * N_RES) / 256, 256, 0, stream>>>(state0, sF, s8_0);
  k_wres_t<<<dim3(64, 64), 256, 0, stream>>>(W_res, WresBT8);
  k_build_b2<<<16384, 256, 0, stream>>>(W_in, W_gate, B2);

  for (int t0 = 0; t0 < T_STEPS; t0 += Tc) {
    k_build_a2<<<Tc * B_SZ, 256, 0, stream>>>(x, A2, t0);
    int Mrows = Tc * B_SZ;
    int mtiles = (Mrows + 255) / 256;
    k_gemm_pre<<<mtiles * 64, 512, 0, stream>>>(A2, B2, ipb, gtb, Mrows);
    for (int tl = 0; tl < Tc; ++tl) {
      int t = t0 + tl;
      const unsigned char* Ar = (t & 1) ? s8_1 : s8_0;
      unsigned char*       Aw = (t & 1) ? s8_0 : s8_1;
      k_step_gemm<<<256, 512, 0, stream>>>(Ar, WresBT8, part);
      k_step_red<<<512, 256, 0, stream>>>(
          part,
          ipb + (size_t)tl * B_SZ * N_RES,
          gtb + (size_t)tl * B_SZ * 12288,
          sF, Aw,
          out + (size_t)t * B_SZ * MAXD);
    }
  }
}

// Round 17
// 2372.274 us; speedup vs baseline: 1.9378x; 1.0211x over previous
//
#include <hip/hip_runtime.h>
#include <hip/hip_bf16.h>
#include <hip/hip_fp16.h>

#define N_RES   4096
#define MAXD    4608
#define IN_DIM  1024
#define T_STEPS 128
#define B_SZ    128

typedef __attribute__((ext_vector_type(8))) short bf16x8;
typedef __attribute__((ext_vector_type(8))) _Float16 f16x8;
typedef __attribute__((ext_vector_type(4))) float f32x4;

__device__ __forceinline__ short f2bf(float x) {
  union { float f; unsigned u; } v; v.f = x;
  unsigned r = v.u + 0x7fffu + ((v.u >> 16) & 1u);
  return (short)(r >> 16);
}
__device__ __forceinline__ short f2h(float x) {
  union { _Float16 h; short s; } u; u.h = (_Float16)x; return u.s;
}
__device__ __forceinline__ float h2f(short s) {
  union { _Float16 h; short s; } u; u.s = s; return (float)u.h;
}
// float -> OCP e4m3 (RNE, satfinite) via v_cvt_pk_fp8_f32 (gfx950 = OCP)
__device__ __forceinline__ unsigned char f2fp8(float x) {
  return (unsigned char)(__builtin_amdgcn_cvt_pk_fp8_f32(x, 0.f, 0, false) & 0xff);
}

__device__ __forceinline__ void gload16(const void* g, void* l) {
  __builtin_amdgcn_global_load_lds(
      (const __attribute__((address_space(1))) void*)g,
      (__attribute__((address_space(3))) void*)l,
      16, 0, 0);
}

// ---------------- zero ONLY the padding columns [4096,4608) ----------------
__global__ void k_zero_pad(float* __restrict__ out) {
  int row = blockIdx.x;            // 16384 rows (T*B)
  int t = threadIdx.x;             // 128 threads * float4 = 512 cols
  *(float4*)(out + (size_t)row * MAXD + N_RES + t * 4) = float4{0.f, 0.f, 0.f, 0.f};
}

// ---------------- init fp8 state from state0 ----------------
__global__ void k_init_s8(const float* __restrict__ s0,
                          unsigned char* __restrict__ s8) {
  int i = blockIdx.x * 256 + threadIdx.x;   // 128*4096 total
  int m = i >> 12, n = i & 4095;
  s8[i] = f2fp8(s0[m * MAXD + n]);
}

// ---------------- transpose W_res -> fp8 [n][k] ----------------
__global__ void k_wres_t(const float* __restrict__ W, unsigned char* __restrict__ bt) {
  __shared__ float tile[64][65];
  int k0 = blockIdx.y * 64, n0 = blockIdx.x * 64;
  int tx = threadIdx.x & 63, ty = threadIdx.x >> 6;   // 256 thr
  #pragma unroll
  for (int r = 0; r < 64; r += 4)
    tile[r + ty][tx] = W[(long)(k0 + r + ty) * N_RES + n0 + tx];
  __syncthreads();
  #pragma unroll
  for (int r = 0; r < 64; r += 4)
    bt[(long)(n0 + r + ty) * N_RES + k0 + tx] = f2fp8(tile[tx][r + ty]);
}

// ---------------- build B2 = fp16 rows of [W_in;W_gate]  [16384][1024] ---------
__global__ void k_build_b2(const float* __restrict__ Win,
                           const float* __restrict__ Wg, short* __restrict__ B2) {
  int r = blockIdx.x;   // 16384 rows
  const float* src = (r < N_RES) ? (Win + (long)r * IN_DIM)
                                 : (Wg + (long)(r - N_RES) * IN_DIM);
  short* dst = B2 + (long)r * IN_DIM;
  for (int c = threadIdx.x; c < IN_DIM; c += 256)
    dst[c] = f2h(src[c]);
}

// ---------------- build A2 = fp16 x chunk  [Tc*128][1024] ----------------
__global__ void k_build_a2(const float* __restrict__ x, short* __restrict__ A2, int t0) {
  int r = blockIdx.x;   // Tc*128 rows
  const float* src = x + (long)(t0 * B_SZ + r) * IN_DIM;
  short* dst = A2 + (long)r * IN_DIM;
  for (int c = threadIdx.x; c < IN_DIM; c += 256)
    dst[c] = f2h(src[c]);
}

// ---------------- precompute GEMM: C = A2 @ B2^T  (256x256 8-phase, fp16 K=1024) --
// Frozen from R12. Gates stored u8 (x255), ip stored f16.
__global__ __launch_bounds__(512, 2) void k_gemm_pre(
    const short* __restrict__ A2, const short* __restrict__ B2,
    _Float16* __restrict__ ip, unsigned char* __restrict__ gates, int Mrows) {
  __shared__ short lA[2][2][128 * 64];
  __shared__ short lB[2][2][128 * 64];
  int tid = threadIdx.x, lane = tid & 63, wid = tid >> 6;
  int wr = wid >> 2, wc = wid & 3;

  int nwg = gridDim.x, orig = blockIdx.x;
  int mtiles = nwg >> 6;
  int mt, nt;
  if ((mtiles & 3) == 0) {
    int xcd = orig & 7, idx = orig >> 3;
    int w = idx & 31, sq = idx >> 5;
    nt = xcd * 8 + (w & 7);
    mt = sq * 4 + (w >> 3);
  } else {
    int qx = nwg >> 3, rx = nwg & 7, xcd = orig & 7;
    int wgid = (xcd < rx ? xcd * (qx + 1) : rx * (qx + 1) + (xcd - rx) * qx) + (orig >> 3);
    mt = wgid >> 6; nt = wgid & 63;
  }
  long m0 = (long)mt * 256, n0 = (long)nt * 256;
  long mclamp = Mrows - 1;

  int c0 = tid, c1 = 512 + tid;
  int r0 = c0 >> 3, r1 = c1 >> 3;
  int cc0 = ((c0 & 7) ^ (r0 & 7)) * 8, cc1 = ((c1 & 7) ^ (r1 & 7)) * 8;

  const short *pA00, *pA01, *pA10, *pA11, *pB00, *pB01, *pB10, *pB11;
  {
    long a00 = m0 + r0;       if (a00 > mclamp) a00 = mclamp;
    long a01 = m0 + r1;       if (a01 > mclamp) a01 = mclamp;
    long a10 = m0 + 128 + r0; if (a10 > mclamp) a10 = mclamp;
    long a11 = m0 + 128 + r1; if (a11 > mclamp) a11 = mclamp;
    pA00 = A2 + a00 * IN_DIM + cc0;  pA01 = A2 + a01 * IN_DIM + cc1;
    pA10 = A2 + a10 * IN_DIM + cc0;  pA11 = A2 + a11 * IN_DIM + cc1;
    pB00 = B2 + (n0 + r0) * IN_DIM + cc0;        pB01 = B2 + (n0 + r1) * IN_DIM + cc1;
    pB10 = B2 + (n0 + 128 + r0) * IN_DIM + cc0;  pB11 = B2 + (n0 + 128 + r1) * IN_DIM + cc1;
  }

  #define STG_A0(kt, b) { gload16(pA00 + (kt)*64, &lA[b][0][c0*8]); gload16(pA01 + (kt)*64, &lA[b][0][c1*8]); }
  #define STG_A1(kt, b) { gload16(pA10 + (kt)*64, &lA[b][1][c0*8]); gload16(pA11 + (kt)*64, &lA[b][1][c1*8]); }
  #define STG_B0(kt, b) { gload16(pB00 + (kt)*64, &lB[b][0][c0*8]); gload16(pB01 + (kt)*64, &lB[b][0][c1*8]); }
  #define STG_B1(kt, b) { gload16(pB10 + (kt)*64, &lB[b][1][c0*8]); gload16(pB11 + (kt)*64, &lB[b][1][c1*8]); }

  int lm = lane & 15;
  int colS0 = ((lane >> 4) * 8) ^ ((lane & 7) << 3);
  int colS1 = (32 + (lane >> 4) * 8) ^ ((lane & 7) << 3);
  int arow[4], brow[2];
  #pragma unroll
  for (int i = 0; i < 4; ++i) arow[i] = (wr * 64 + i * 16 + lm) * 64;
  #pragma unroll
  for (int j = 0; j < 2; ++j) brow[j] = (wc * 32 + j * 16 + lm) * 64;

  f16x8 aF[4][2], bFh[2][2][2];
  f32x4 acc[2][4][4] = {};

  #define RD_A(qm, b) { _Pragma("unroll") for (int i = 0; i < 4; ++i) {        \
      aF[i][0] = *(const f16x8*)&lA[b][qm][arow[i] + colS0];                   \
      aF[i][1] = *(const f16x8*)&lA[b][qm][arow[i] + colS1]; } }
  #define RD_B(h, b) { _Pragma("unroll") for (int j = 0; j < 2; ++j) {         \
      bFh[h][j][0] = *(const f16x8*)&lB[b][h][brow[j] + colS0];                \
      bFh[h][j][1] = *(const f16x8*)&lB[b][h][brow[j] + colS1]; } }
  #define MM(qm, qn) { __builtin_amdgcn_s_setprio(1);                          \
      _Pragma("unroll") for (int i = 0; i < 4; ++i)                            \
      _Pragma("unroll") for (int j = 0; j < 2; ++j) {                          \
        acc[qm][i][(qn)*2+j] = __builtin_amdgcn_mfma_f32_16x16x32_f16(         \
            aF[i][0], bFh[qn][j][0], acc[qm][i][(qn)*2+j], 0, 0, 0);           \
        acc[qm][i][(qn)*2+j] = __builtin_amdgcn_mfma_f32_16x16x32_f16(         \
            aF[i][1], bFh[qn][j][1], acc[qm][i][(qn)*2+j], 0, 0, 0); }         \
      __builtin_amdgcn_s_setprio(0); }

  STG_A0(0, 0); STG_B0(0, 0); STG_B1(0, 0); STG_A1(0, 0);

  const int nk = IN_DIM / 64;   // 16
  for (int kt = 0; kt < nk; ++kt) {
    int buf = kt & 1, nbuf = buf ^ 1;
    int ktn = (kt + 1 < nk) ? kt + 1 : kt;
    asm volatile("s_waitcnt vmcnt(4)\n\ts_barrier" ::: "memory");
    RD_A(0, buf); RD_B(0, buf);
    STG_A0(ktn, nbuf);
    MM(0, 0);
    asm volatile("s_barrier" ::: "memory");
    asm volatile("s_waitcnt vmcnt(4)\n\ts_barrier" ::: "memory");
    RD_B(1, buf);
    STG_B0(ktn, nbuf);
    MM(0, 1);
    asm volatile("s_barrier" ::: "memory");
    asm volatile("s_waitcnt vmcnt(4)\n\ts_barrier" ::: "memory");
    RD_A(1, buf);
    STG_B1(ktn, nbuf);
    MM(1, 0);
    asm volatile("s_barrier" ::: "memory");
    STG_A1(ktn, nbuf);
    MM(1, 1);
    asm volatile("s_barrier" ::: "memory");
  }
  #undef STG_A0
  #undef STG_A1
  #undef STG_B0
  #undef STG_B1
  #undef RD_A
  #undef RD_B
  #undef MM

  #pragma unroll
  for (int qm = 0; qm < 2; ++qm)
    #pragma unroll
    for (int i = 0; i < 4; ++i)
      #pragma unroll
      for (int qn = 0; qn < 2; ++qn)
        #pragma unroll
        for (int j = 0; j < 2; ++j)
          #pragma unroll
          for (int q = 0; q < 4; ++q) {
            long m = m0 + qm * 128 + wr * 64 + i * 16 + (lane >> 4) * 4 + q;
            long n = n0 + qn * 128 + wc * 32 + j * 16 + lm;
            if (m >= Mrows) continue;
            float v = acc[qm][i][qn * 2 + j][q];
            if (n < N_RES) {
              ip[m * N_RES + n] = (_Float16)v;
            } else {
              float g = 1.f / (1.f + __expf(-v));
              gates[m * 12288 + (n - N_RES)] = (unsigned char)(g * 255.f + 0.5f);
            }
          }
}

// ---------------- per-step GEMM (K-split, fp8 operands) ----------------
// 256 blocks = 2 m_h x 4 kc x 32 n_t. BM=64, BN=128, Kc=1024 fp8 elems,
// BK=256 elems = 256 B/row. 4 K-tiles, 3-buffer depth-2 counted pipeline
// (vmcnt(6)). Partials f16. PROVEN in R13 — do not modify.
__global__ __launch_bounds__(512) void k_step_gemm(
    const unsigned char* __restrict__ A8,  // state fp8 (read buf) [128][4096]
    const unsigned char* __restrict__ B8,  // Wres^T fp8 [4096][4096]
    short* __restrict__ part) {            // [4][128][4096] f16
  __shared__ unsigned char lA[3][64 * 256];    // 3 x 16 KiB
  __shared__ unsigned char lB[3][128 * 256];   // 3 x 32 KiB (total 144 KiB)
  int tid = threadIdx.x, lane = tid & 63, wid = tid >> 6;   // 8 waves
  int wm = wid >> 2, wn = wid & 3;      // wave tile 32x32 (2m x 4n waves)

  int b = blockIdx.x;
  int xcd = b & 7, i2 = b >> 3;
  int m_h = i2 & 1, kc = (i2 >> 1) & 3, n_tl = i2 >> 3;   // 0..3
  int n_t = xcd * 4 + n_tl;             // 0..31
  int m0 = m_h * 64, n0 = n_t * 128, kb = kc * 1024;      // kb in elems

  // staging: A 64x256B = 1024 16B-chunks (2/thr), B 128x256B = 2048 (4/thr)
  // chunk c: row=c>>4, colchunk=(c&15)^(row&7); dest linear c*16B.
  const unsigned char* pA[2];
  const unsigned char* pB[4];
  #pragma unroll
  for (int i = 0; i < 2; ++i) {
    int c = i * 512 + tid, row = c >> 4;
    pA[i] = A8 + (size_t)(m0 + row) * N_RES + kb + (((c & 15) ^ (row & 7)) * 16);
  }
  #pragma unroll
  for (int i = 0; i < 4; ++i) {
    int c = i * 512 + tid, row = c >> 4;
    pB[i] = B8 + (size_t)(n0 + row) * N_RES + kb + (((c & 15) ^ (row & 7)) * 16);
  }

  #define STAGE(kt, bi) { int k0s = (kt) * 256;                                \
    _Pragma("unroll") for (int i = 0; i < 2; ++i)                              \
      gload16(pA[i] + k0s, &lA[bi][(i * 512 + tid) * 16]);                     \
    _Pragma("unroll") for (int i = 0; i < 4; ++i)                              \
      gload16(pB[i] + k0s, &lB[bi][(i * 512 + tid) * 16]); }

  f32x4 acc[2][2] = {};

  // fragment: lane holds 8 consecutive fp8 at k = (lane>>4)*8 (+kk), row = base+(lane&15)
  // swizzled byte col: b ^ ((lane&7)<<4)  (row&7 == lane&7 for all our rows)
  #define COMPUTE(bi)                                                          \
    { _Pragma("unroll")                                                        \
      for (int kk = 0; kk < 256; kk += 32) {                                   \
        int colS = (kk + (lane >> 4) * 8) ^ ((lane & 7) << 4);                 \
        long aF0 = *(const long*)&lA[bi][(wm * 32 + (lane & 15)) * 256 + colS];      \
        long aF1 = *(const long*)&lA[bi][(wm * 32 + 16 + (lane & 15)) * 256 + colS]; \
        long bF0 = *(const long*)&lB[bi][(wn * 32 + (lane & 15)) * 256 + colS];      \
        long bF1 = *(const long*)&lB[bi][(wn * 32 + 16 + (lane & 15)) * 256 + colS]; \
        acc[0][0] = __builtin_amdgcn_mfma_f32_16x16x32_fp8_fp8(aF0, bF0, acc[0][0], 0, 0, 0); \
        acc[0][1] = __builtin_amdgcn_mfma_f32_16x16x32_fp8_fp8(aF0, bF1, acc[0][1], 0, 0, 0); \
        acc[1][0] = __builtin_amdgcn_mfma_f32_16x16x32_fp8_fp8(aF1, bF0, acc[1][0], 0, 0, 0); \
        acc[1][1] = __builtin_amdgcn_mfma_f32_16x16x32_fp8_fp8(aF1, bF1, acc[1][1], 0, 0, 0); \
      } }

  STAGE(0, 0);
  STAGE(1, 1);                          // 12 loads in flight

  int bi = 0, sb = 2;
  for (int kt = 0; kt < 3; ++kt) {      // tiles 0..2; tile 3 in tail
    asm volatile("s_waitcnt vmcnt(6)" ::: "memory");
    __builtin_amdgcn_s_barrier();
    if (kt < 2) STAGE(kt + 2, sb);
    COMPUTE(bi);
    ++bi; if (bi == 3) bi = 0;
    ++sb; if (sb == 3) sb = 0;
  }
  asm volatile("s_waitcnt vmcnt(0)" ::: "memory");
  __builtin_amdgcn_s_barrier();
  COMPUTE(bi);                          // tile 3 (bi == 0)
  #undef STAGE
  #undef COMPUTE

  short* dst = part + (size_t)kc * (B_SZ * N_RES);
  #pragma unroll
  for (int i = 0; i < 2; ++i)
    #pragma unroll
    for (int j = 0; j < 2; ++j)
      #pragma unroll
      for (int q = 0; q < 4; ++q) {
        int m = m0 + wm * 32 + i * 16 + (lane >> 4) * 4 + q;
        int n = n0 + wn * 32 + j * 16 + (lane & 15);
        dst[(size_t)m * N_RES + n] = f2h(acc[i][j][q]);
      }
}

// ---------------- per-step reduce + gate epilogue ----------------
// 512 blocks x 256 thr, 4 elems/thread. Sums 4 fp16 K-partials, applies u8
// gates / tanh / spike. State lives in `out` (prev = state0 or out[t-1], both
// stride MAXD); writes out[t] + fp8 state only (sF eliminated, bit-identical).
__global__ void k_step_red(
    const short* __restrict__ part,     // [4][128][4096] f16
    const _Float16* __restrict__ ip,    // [128][4096]
    const unsigned char* __restrict__ gt, // [128][12288] u8
    const float* __restrict__ prev,     // prev state, stride MAXD
    unsigned char* __restrict__ s8w,    // fp8 state (write buf)
    float* __restrict__ out) {          // d_out + t*128*4608
  int e = (blockIdx.x * 256 + threadIdx.x) * 4;
  int m = e >> 12, n = e & 4095;
  float res[4] = {0.f, 0.f, 0.f, 0.f};
  #pragma unroll
  for (int k = 0; k < 4; ++k) {
    short4 p = *(const short4*)(part + ((size_t)k << 19) + e);
    res[0] += h2f(p.x); res[1] += h2f(p.y); res[2] += h2f(p.z); res[3] += h2f(p.w);
  }
  short4 ipr = *(const short4*)((const short*)ip + e);
  const unsigned char* g = gt + (size_t)m * 12288 + n;
  uchar4 igr = *(const uchar4*)g;
  uchar4 fgr = *(const uchar4*)(g + 4096);
  uchar4 ogr = *(const uchar4*)(g + 8192);
  float4 pr = *(const float4*)(prev + (size_t)m * MAXD + n);

  float prv[4] = { pr.x, pr.y, pr.z, pr.w };
  short ipa[4] = { ipr.x, ipr.y, ipr.z, ipr.w };
  unsigned char iga[4] = { igr.x, igr.y, igr.z, igr.w };
  unsigned char fga[4] = { fgr.x, fgr.y, fgr.z, fgr.w };
  unsigned char oga[4] = { ogr.x, ogr.y, ogr.z, ogr.w };

  const float is = 1.f / 255.f;
  float so[4];
  unsigned char s8[4];
  #pragma unroll
  for (int q = 0; q < 4; ++q) {
    float s = 0.9f * ((float)fga[q] * is * prv[q])
            + 0.1f * tanhf((float)iga[q] * is * (h2f(ipa[q]) + res[q]));
    s = (float)oga[q] * is * s;
    if (s > 0.5f) s -= 0.5f;
    so[q] = s;
    s8[q] = f2fp8(s);
  }
  *(float4*)(out + (size_t)m * MAXD + n) = float4{so[0], so[1], so[2], so[3]};
  *(uchar4*)(s8w + e) = uchar4{s8[0], s8[1], s8[2], s8[3]};
}

extern "C" void kernel_launch(void* const* d_in, const int* in_sizes, int n_in,
                              void* d_out, int out_size, void* d_ws, size_t ws_size,
                              hipStream_t stream) {
  const float* x      = (const float*)d_in[0];
  const float* state0 = (const float*)d_in[1];
  const float* W_res  = (const float*)d_in[2];
  const float* W_in   = (const float*)d_in[3];
  const float* W_gate = (const float*)d_in[4];
  float* out = (float*)d_out;
  char* ws = (char*)d_ws;

  size_t off = 0;
  unsigned char* WresBT8 = (unsigned char*)(ws + off); off += (size_t)N_RES * N_RES;  // 16.8 MB
  short* B2     = (short*)(ws + off); off += (size_t)16384 * IN_DIM * 2;      // 33.6 MB
  unsigned char* s8_0 = (unsigned char*)(ws + off); off += (size_t)B_SZ * N_RES;  // 0.5 MB
  unsigned char* s8_1 = (unsigned char*)(ws + off); off += (size_t)B_SZ * N_RES;  // 0.5 MB
  short* part   = (short*)(ws + off); off += (size_t)4 * B_SZ * N_RES * 2;    // 4 MB
  size_t fixed = off;
  size_t per = (size_t)B_SZ * IN_DIM * 2 + (size_t)B_SZ * N_RES * 2 + (size_t)B_SZ * 12288;

  int Tc = T_STEPS;
  while (Tc > 1 && fixed + (size_t)Tc * per > ws_size) Tc >>= 1;

  short*          A2  = (short*)(ws + fixed);
  _Float16*       ipb = (_Float16*)(ws + fixed + (size_t)Tc * B_SZ * IN_DIM * 2);
  unsigned char*  gtb = (unsigned char*)(ws + fixed + (size_t)Tc * B_SZ * IN_DIM * 2
                                         + (size_t)Tc * B_SZ * N_RES * 2);

  k_zero_pad<<<T_STEPS * B_SZ, 128, 0, stream>>>(out);
  k_init_s8<<<(B_SZ * N_RES) / 256, 256, 0, stream>>>(state0, s8_0);
  k_wres_t<<<dim3(64, 64), 256, 0, stream>>>(W_res, WresBT8);
  k_build_b2<<<16384, 256, 0, stream>>>(W_in, W_gate, B2);

  for (int t0 = 0; t0 < T_STEPS; t0 += Tc) {
    k_build_a2<<<Tc * B_SZ, 256, 0, stream>>>(x, A2, t0);
    int Mrows = Tc * B_SZ;
    int mtiles = (Mrows + 255) / 256;
    k_gemm_pre<<<mtiles * 64, 512, 0, stream>>>(A2, B2, ipb, gtb, Mrows);
    for (int tl = 0; tl < Tc; ++tl) {
      int t = t0 + tl;
      const unsigned char* Ar = (t & 1) ? s8_1 : s8_0;
      unsigned char*       Aw = (t & 1) ? s8_0 : s8_1;
      const float* prev = (t == 0) ? state0 : out + (size_t)(t - 1) * B_SZ * MAXD;
      k_step_gemm<<<256, 512, 0, stream>>>(Ar, WresBT8, part);
      k_step_red<<<512, 256, 0, stream>>>(
          part,
          ipb + (size_t)tl * B_SZ * N_RES,
          gtb + (size_t)tl * B_SZ * 12288,
          prev, Aw,
          out + (size_t)t * B_SZ * MAXD);
    }
  }
}

// Round 18
// 2357.542 us; speedup vs baseline: 1.9499x; 1.0062x over previous
//
#include <hip/hip_runtime.h>
#include <hip/hip_bf16.h>
#include <hip/hip_fp16.h>

#define N_RES   4096
#define MAXD    4608
#define IN_DIM  1024
#define T_STEPS 128
#define B_SZ    128

typedef __attribute__((ext_vector_type(8))) short bf16x8;
typedef __attribute__((ext_vector_type(8))) _Float16 f16x8;
typedef __attribute__((ext_vector_type(4))) float f32x4;

__device__ __forceinline__ short f2bf(float x) {
  union { float f; unsigned u; } v; v.f = x;
  unsigned r = v.u + 0x7fffu + ((v.u >> 16) & 1u);
  return (short)(r >> 16);
}
__device__ __forceinline__ short f2h(float x) {
  union { _Float16 h; short s; } u; u.h = (_Float16)x; return u.s;
}
__device__ __forceinline__ float h2f(short s) {
  union { _Float16 h; short s; } u; u.s = s; return (float)u.h;
}
// float -> OCP e4m3 (RNE, satfinite) via v_cvt_pk_fp8_f32 (gfx950 = OCP)
__device__ __forceinline__ unsigned char f2fp8(float x) {
  return (unsigned char)(__builtin_amdgcn_cvt_pk_fp8_f32(x, 0.f, 0, false) & 0xff);
}

__device__ __forceinline__ void gload16(const void* g, void* l) {
  __builtin_amdgcn_global_load_lds(
      (const __attribute__((address_space(1))) void*)g,
      (__attribute__((address_space(3))) void*)l,
      16, 0, 0);
}

// ---------------- zero ONLY the padding columns [4096,4608) ----------------
__global__ void k_zero_pad(float* __restrict__ out) {
  int row = blockIdx.x;            // 16384 rows (T*B)
  int t = threadIdx.x;             // 128 threads * float4 = 512 cols
  *(float4*)(out + (size_t)row * MAXD + N_RES + t * 4) = float4{0.f, 0.f, 0.f, 0.f};
}

// ---------------- init fp8 state from state0 (vectorized) ----------------
__global__ void k_init_s8(const float* __restrict__ s0,
                          unsigned char* __restrict__ s8) {
  int i = (blockIdx.x * 256 + threadIdx.x) * 4;   // 128*4096 total
  int m = i >> 12, n = i & 4095;
  float4 v = *(const float4*)(s0 + (size_t)m * MAXD + n);
  uchar4 o = { f2fp8(v.x), f2fp8(v.y), f2fp8(v.z), f2fp8(v.w) };
  *(uchar4*)(s8 + i) = o;
}

// ---------------- transpose W_res -> fp8 [n][k] (uchar4 stores) ----------------
__global__ void k_wres_t(const float* __restrict__ W, unsigned char* __restrict__ bt) {
  __shared__ float tile[64][65];
  int k0 = blockIdx.y * 64, n0 = blockIdx.x * 64;
  int tx = threadIdx.x & 63, ty = threadIdx.x >> 6;   // 256 thr
  #pragma unroll
  for (int r = 0; r < 64; r += 4)
    tile[r + ty][tx] = W[(long)(k0 + r + ty) * N_RES + n0 + tx];
  __syncthreads();
  // bt[n0+row][k0+q*4+j] = tile[q*4+j][row]  (same mapping as scalar version)
  #pragma unroll
  for (int it = 0; it < 4; ++it) {
    int slot = it * 256 + threadIdx.x;
    int row = slot >> 4, q = (slot & 15) * 4;
    uchar4 o = { f2fp8(tile[q][row]), f2fp8(tile[q + 1][row]),
                 f2fp8(tile[q + 2][row]), f2fp8(tile[q + 3][row]) };
    *(uchar4*)(bt + (long)(n0 + row) * N_RES + k0 + q) = o;
  }
}

// ---------------- build B2 = fp16 rows of [W_in;W_gate] (vectorized) ----------
__global__ void k_build_b2(const float* __restrict__ Win,
                           const float* __restrict__ Wg, short* __restrict__ B2) {
  int r = blockIdx.x;   // 16384 rows
  const float* src = (r < N_RES) ? (Win + (long)r * IN_DIM)
                                 : (Wg + (long)(r - N_RES) * IN_DIM);
  short* dst = B2 + (long)r * IN_DIM;
  int c = threadIdx.x * 4;   // 256 thr x 4 = 1024
  float4 v = *(const float4*)(src + c);
  short4 o = { f2h(v.x), f2h(v.y), f2h(v.z), f2h(v.w) };
  *(short4*)(dst + c) = o;
}

// ---------------- build A2 = fp16 x chunk (vectorized) ----------------
__global__ void k_build_a2(const float* __restrict__ x, short* __restrict__ A2, int t0) {
  int r = blockIdx.x;   // Tc*128 rows
  const float* src = x + (long)(t0 * B_SZ + r) * IN_DIM;
  short* dst = A2 + (long)r * IN_DIM;
  int c = threadIdx.x * 4;
  float4 v = *(const float4*)(src + c);
  short4 o = { f2h(v.x), f2h(v.y), f2h(v.z), f2h(v.w) };
  *(short4*)(dst + c) = o;
}

// ---------------- precompute GEMM: C = A2 @ B2^T  (256x256 8-phase, fp16 K=1024) --
// Frozen from R12. Gates stored u8 (x255), ip stored f16.
__global__ __launch_bounds__(512, 2) void k_gemm_pre(
    const short* __restrict__ A2, const short* __restrict__ B2,
    _Float16* __restrict__ ip, unsigned char* __restrict__ gates, int Mrows) {
  __shared__ short lA[2][2][128 * 64];
  __shared__ short lB[2][2][128 * 64];
  int tid = threadIdx.x, lane = tid & 63, wid = tid >> 6;
  int wr = wid >> 2, wc = wid & 3;

  int nwg = gridDim.x, orig = blockIdx.x;
  int mtiles = nwg >> 6;
  int mt, nt;
  if ((mtiles & 3) == 0) {
    int xcd = orig & 7, idx = orig >> 3;
    int w = idx & 31, sq = idx >> 5;
    nt = xcd * 8 + (w & 7);
    mt = sq * 4 + (w >> 3);
  } else {
    int qx = nwg >> 3, rx = nwg & 7, xcd = orig & 7;
    int wgid = (xcd < rx ? xcd * (qx + 1) : rx * (qx + 1) + (xcd - rx) * qx) + (orig >> 3);
    mt = wgid >> 6; nt = wgid & 63;
  }
  long m0 = (long)mt * 256, n0 = (long)nt * 256;
  long mclamp = Mrows - 1;

  int c0 = tid, c1 = 512 + tid;
  int r0 = c0 >> 3, r1 = c1 >> 3;
  int cc0 = ((c0 & 7) ^ (r0 & 7)) * 8, cc1 = ((c1 & 7) ^ (r1 & 7)) * 8;

  const short *pA00, *pA01, *pA10, *pA11, *pB00, *pB01, *pB10, *pB11;
  {
    long a00 = m0 + r0;       if (a00 > mclamp) a00 = mclamp;
    long a01 = m0 + r1;       if (a01 > mclamp) a01 = mclamp;
    long a10 = m0 + 128 + r0; if (a10 > mclamp) a10 = mclamp;
    long a11 = m0 + 128 + r1; if (a11 > mclamp) a11 = mclamp;
    pA00 = A2 + a00 * IN_DIM + cc0;  pA01 = A2 + a01 * IN_DIM + cc1;
    pA10 = A2 + a10 * IN_DIM + cc0;  pA11 = A2 + a11 * IN_DIM + cc1;
    pB00 = B2 + (n0 + r0) * IN_DIM + cc0;        pB01 = B2 + (n0 + r1) * IN_DIM + cc1;
    pB10 = B2 + (n0 + 128 + r0) * IN_DIM + cc0;  pB11 = B2 + (n0 + 128 + r1) * IN_DIM + cc1;
  }

  #define STG_A0(kt, b) { gload16(pA00 + (kt)*64, &lA[b][0][c0*8]); gload16(pA01 + (kt)*64, &lA[b][0][c1*8]); }
  #define STG_A1(kt, b) { gload16(pA10 + (kt)*64, &lA[b][1][c0*8]); gload16(pA11 + (kt)*64, &lA[b][1][c1*8]); }
  #define STG_B0(kt, b) { gload16(pB00 + (kt)*64, &lB[b][0][c0*8]); gload16(pB01 + (kt)*64, &lB[b][0][c1*8]); }
  #define STG_B1(kt, b) { gload16(pB10 + (kt)*64, &lB[b][1][c0*8]); gload16(pB11 + (kt)*64, &lB[b][1][c1*8]); }

  int lm = lane & 15;
  int colS0 = ((lane >> 4) * 8) ^ ((lane & 7) << 3);
  int colS1 = (32 + (lane >> 4) * 8) ^ ((lane & 7) << 3);
  int arow[4], brow[2];
  #pragma unroll
  for (int i = 0; i < 4; ++i) arow[i] = (wr * 64 + i * 16 + lm) * 64;
  #pragma unroll
  for (int j = 0; j < 2; ++j) brow[j] = (wc * 32 + j * 16 + lm) * 64;

  f16x8 aF[4][2], bFh[2][2][2];
  f32x4 acc[2][4][4] = {};

  #define RD_A(qm, b) { _Pragma("unroll") for (int i = 0; i < 4; ++i) {        \
      aF[i][0] = *(const f16x8*)&lA[b][qm][arow[i] + colS0];                   \
      aF[i][1] = *(const f16x8*)&lA[b][qm][arow[i] + colS1]; } }
  #define RD_B(h, b) { _Pragma("unroll") for (int j = 0; j < 2; ++j) {         \
      bFh[h][j][0] = *(const f16x8*)&lB[b][h][brow[j] + colS0];                \
      bFh[h][j][1] = *(const f16x8*)&lB[b][h][brow[j] + colS1]; } }
  #define MM(qm, qn) { __builtin_amdgcn_s_setprio(1);                          \
      _Pragma("unroll") for (int i = 0; i < 4; ++i)                            \
      _Pragma("unroll") for (int j = 0; j < 2; ++j) {                          \
        acc[qm][i][(qn)*2+j] = __builtin_amdgcn_mfma_f32_16x16x32_f16(         \
            aF[i][0], bFh[qn][j][0], acc[qm][i][(qn)*2+j], 0, 0, 0);           \
        acc[qm][i][(qn)*2+j] = __builtin_amdgcn_mfma_f32_16x16x32_f16(         \
            aF[i][1], bFh[qn][j][1], acc[qm][i][(qn)*2+j], 0, 0, 0); }         \
      __builtin_amdgcn_s_setprio(0); }

  STG_A0(0, 0); STG_B0(0, 0); STG_B1(0, 0); STG_A1(0, 0);

  const int nk = IN_DIM / 64;   // 16
  for (int kt = 0; kt < nk; ++kt) {
    int buf = kt & 1, nbuf = buf ^ 1;
    int ktn = (kt + 1 < nk) ? kt + 1 : kt;
    asm volatile("s_waitcnt vmcnt(4)\n\ts_barrier" ::: "memory");
    RD_A(0, buf); RD_B(0, buf);
    STG_A0(ktn, nbuf);
    MM(0, 0);
    asm volatile("s_barrier" ::: "memory");
    asm volatile("s_waitcnt vmcnt(4)\n\ts_barrier" ::: "memory");
    RD_B(1, buf);
    STG_B0(ktn, nbuf);
    MM(0, 1);
    asm volatile("s_barrier" ::: "memory");
    asm volatile("s_waitcnt vmcnt(4)\n\ts_barrier" ::: "memory");
    RD_A(1, buf);
    STG_B1(ktn, nbuf);
    MM(1, 0);
    asm volatile("s_barrier" ::: "memory");
    STG_A1(ktn, nbuf);
    MM(1, 1);
    asm volatile("s_barrier" ::: "memory");
  }
  #undef STG_A0
  #undef STG_A1
  #undef STG_B0
  #undef STG_B1
  #undef RD_A
  #undef RD_B
  #undef MM

  #pragma unroll
  for (int qm = 0; qm < 2; ++qm)
    #pragma unroll
    for (int i = 0; i < 4; ++i)
      #pragma unroll
      for (int qn = 0; qn < 2; ++qn)
        #pragma unroll
        for (int j = 0; j < 2; ++j)
          #pragma unroll
          for (int q = 0; q < 4; ++q) {
            long m = m0 + qm * 128 + wr * 64 + i * 16 + (lane >> 4) * 4 + q;
            long n = n0 + qn * 128 + wc * 32 + j * 16 + lm;
            if (m >= Mrows) continue;
            float v = acc[qm][i][qn * 2 + j][q];
            if (n < N_RES) {
              ip[m * N_RES + n] = (_Float16)v;
            } else {
              float g = 1.f / (1.f + __expf(-v));
              gates[m * 12288 + (n - N_RES)] = (unsigned char)(g * 255.f + 0.5f);
            }
          }
}

// ---------------- per-step GEMM (K-split, fp8 operands) ----------------
// 256 blocks = 2 m_h x 4 kc x 32 n_t. BM=64, BN=128, Kc=1024 fp8 elems,
// BK=256 elems = 256 B/row. 4 K-tiles, 3-buffer depth-2 counted pipeline
// (vmcnt(6)). Partials f16. PROVEN in R13 — do not modify.
__global__ __launch_bounds__(512) void k_step_gemm(
    const unsigned char* __restrict__ A8,  // state fp8 (read buf) [128][4096]
    const unsigned char* __restrict__ B8,  // Wres^T fp8 [4096][4096]
    short* __restrict__ part) {            // [4][128][4096] f16
  __shared__ unsigned char lA[3][64 * 256];    // 3 x 16 KiB
  __shared__ unsigned char lB[3][128 * 256];   // 3 x 32 KiB (total 144 KiB)
  int tid = threadIdx.x, lane = tid & 63, wid = tid >> 6;   // 8 waves
  int wm = wid >> 2, wn = wid & 3;      // wave tile 32x32 (2m x 4n waves)

  int b = blockIdx.x;
  int xcd = b & 7, i2 = b >> 3;
  int m_h = i2 & 1, kc = (i2 >> 1) & 3, n_tl = i2 >> 3;   // 0..3
  int n_t = xcd * 4 + n_tl;             // 0..31
  int m0 = m_h * 64, n0 = n_t * 128, kb = kc * 1024;      // kb in elems

  // staging: A 64x256B = 1024 16B-chunks (2/thr), B 128x256B = 2048 (4/thr)
  // chunk c: row=c>>4, colchunk=(c&15)^(row&7); dest linear c*16B.
  const unsigned char* pA[2];
  const unsigned char* pB[4];
  #pragma unroll
  for (int i = 0; i < 2; ++i) {
    int c = i * 512 + tid, row = c >> 4;
    pA[i] = A8 + (size_t)(m0 + row) * N_RES + kb + (((c & 15) ^ (row & 7)) * 16);
  }
  #pragma unroll
  for (int i = 0; i < 4; ++i) {
    int c = i * 512 + tid, row = c >> 4;
    pB[i] = B8 + (size_t)(n0 + row) * N_RES + kb + (((c & 15) ^ (row & 7)) * 16);
  }

  #define STAGE(kt, bi) { int k0s = (kt) * 256;                                \
    _Pragma("unroll") for (int i = 0; i < 2; ++i)                              \
      gload16(pA[i] + k0s, &lA[bi][(i * 512 + tid) * 16]);                     \
    _Pragma("unroll") for (int i = 0; i < 4; ++i)                              \
      gload16(pB[i] + k0s, &lB[bi][(i * 512 + tid) * 16]); }

  f32x4 acc[2][2] = {};

  // fragment: lane holds 8 consecutive fp8 at k = (lane>>4)*8 (+kk), row = base+(lane&15)
  // swizzled byte col: b ^ ((lane&7)<<4)  (row&7 == lane&7 for all our rows)
  #define COMPUTE(bi)                                                          \
    { _Pragma("unroll")                                                        \
      for (int kk = 0; kk < 256; kk += 32) {                                   \
        int colS = (kk + (lane >> 4) * 8) ^ ((lane & 7) << 4);                 \
        long aF0 = *(const long*)&lA[bi][(wm * 32 + (lane & 15)) * 256 + colS];      \
        long aF1 = *(const long*)&lA[bi][(wm * 32 + 16 + (lane & 15)) * 256 + colS]; \
        long bF0 = *(const long*)&lB[bi][(wn * 32 + (lane & 15)) * 256 + colS];      \
        long bF1 = *(const long*)&lB[bi][(wn * 32 + 16 + (lane & 15)) * 256 + colS]; \
        acc[0][0] = __builtin_amdgcn_mfma_f32_16x16x32_fp8_fp8(aF0, bF0, acc[0][0], 0, 0, 0); \
        acc[0][1] = __builtin_amdgcn_mfma_f32_16x16x32_fp8_fp8(aF0, bF1, acc[0][1], 0, 0, 0); \
        acc[1][0] = __builtin_amdgcn_mfma_f32_16x16x32_fp8_fp8(aF1, bF0, acc[1][0], 0, 0, 0); \
        acc[1][1] = __builtin_amdgcn_mfma_f32_16x16x32_fp8_fp8(aF1, bF1, acc[1][1], 0, 0, 0); \
      } }

  STAGE(0, 0);
  STAGE(1, 1);                          // 12 loads in flight

  int bi = 0, sb = 2;
  for (int kt = 0; kt < 3; ++kt) {      // tiles 0..2; tile 3 in tail
    asm volatile("s_waitcnt vmcnt(6)" ::: "memory");
    __builtin_amdgcn_s_barrier();
    if (kt < 2) STAGE(kt + 2, sb);
    COMPUTE(bi);
    ++bi; if (bi == 3) bi = 0;
    ++sb; if (sb == 3) sb = 0;
  }
  asm volatile("s_waitcnt vmcnt(0)" ::: "memory");
  __builtin_amdgcn_s_barrier();
  COMPUTE(bi);                          // tile 3 (bi == 0)
  #undef STAGE
  #undef COMPUTE

  short* dst = part + (size_t)kc * (B_SZ * N_RES);
  #pragma unroll
  for (int i = 0; i < 2; ++i)
    #pragma unroll
    for (int j = 0; j < 2; ++j)
      #pragma unroll
      for (int q = 0; q < 4; ++q) {
        int m = m0 + wm * 32 + i * 16 + (lane >> 4) * 4 + q;
        int n = n0 + wn * 32 + j * 16 + (lane & 15);
        dst[(size_t)m * N_RES + n] = f2h(acc[i][j][q]);
      }
}

// ---------------- per-step reduce + gate epilogue ----------------
// 512 blocks x 256 thr, 4 elems/thread. Sums 4 fp16 K-partials, applies u8
// gates / tanh / spike. State lives in `out` (prev = state0 or out[t-1], both
// stride MAXD); writes out[t] + fp8 state only.
__global__ void k_step_red(
    const short* __restrict__ part,     // [4][128][4096] f16
    const _Float16* __restrict__ ip,    // [128][4096]
    const unsigned char* __restrict__ gt, // [128][12288] u8
    const float* __restrict__ prev,     // prev state, stride MAXD
    unsigned char* __restrict__ s8w,    // fp8 state (write buf)
    float* __restrict__ out) {          // d_out + t*128*4608
  int e = (blockIdx.x * 256 + threadIdx.x) * 4;
  int m = e >> 12, n = e & 4095;
  float res[4] = {0.f, 0.f, 0.f, 0.f};
  #pragma unroll
  for (int k = 0; k < 4; ++k) {
    short4 p = *(const short4*)(part + ((size_t)k << 19) + e);
    res[0] += h2f(p.x); res[1] += h2f(p.y); res[2] += h2f(p.z); res[3] += h2f(p.w);
  }
  short4 ipr = *(const short4*)((const short*)ip + e);
  const unsigned char* g = gt + (size_t)m * 12288 + n;
  uchar4 igr = *(const uchar4*)g;
  uchar4 fgr = *(const uchar4*)(g + 4096);
  uchar4 ogr = *(const uchar4*)(g + 8192);
  float4 pr = *(const float4*)(prev + (size_t)m * MAXD + n);

  float prv[4] = { pr.x, pr.y, pr.z, pr.w };
  short ipa[4] = { ipr.x, ipr.y, ipr.z, ipr.w };
  unsigned char iga[4] = { igr.x, igr.y, igr.z, igr.w };
  unsigned char fga[4] = { fgr.x, fgr.y, fgr.z, fgr.w };
  unsigned char oga[4] = { ogr.x, ogr.y, ogr.z, ogr.w };

  const float is = 1.f / 255.f;
  float so[4];
  unsigned char s8[4];
  #pragma unroll
  for (int q = 0; q < 4; ++q) {
    float s = 0.9f * ((float)fga[q] * is * prv[q])
            + 0.1f * tanhf((float)iga[q] * is * (h2f(ipa[q]) + res[q]));
    s = (float)oga[q] * is * s;
    if (s > 0.5f) s -= 0.5f;
    so[q] = s;
    s8[q] = f2fp8(s);
  }
  *(float4*)(out + (size_t)m * MAXD + n) = float4{so[0], so[1], so[2], so[3]};
  *(uchar4*)(s8w + e) = uchar4{s8[0], s8[1], s8[2], s8[3]};
}

extern "C" void kernel_launch(void* const* d_in, const int* in_sizes, int n_in,
                              void* d_out, int out_size, void* d_ws, size_t ws_size,
                              hipStream_t stream) {
  const float* x      = (const float*)d_in[0];
  const float* state0 = (const float*)d_in[1];
  const float* W_res  = (const float*)d_in[2];
  const float* W_in   = (const float*)d_in[3];
  const float* W_gate = (const float*)d_in[4];
  float* out = (float*)d_out;
  char* ws = (char*)d_ws;

  size_t off = 0;
  unsigned char* WresBT8 = (unsigned char*)(ws + off); off += (size_t)N_RES * N_RES;  // 16.8 MB
  short* B2     = (short*)(ws + off); off += (size_t)16384 * IN_DIM * 2;      // 33.6 MB
  unsigned char* s8_0 = (unsigned char*)(ws + off); off += (size_t)B_SZ * N_RES;  // 0.5 MB
  unsigned char* s8_1 = (unsigned char*)(ws + off); off += (size_t)B_SZ * N_RES;  // 0.5 MB
  short* part   = (short*)(ws + off); off += (size_t)4 * B_SZ * N_RES * 2;    // 4 MB
  size_t fixed = off;
  size_t per = (size_t)B_SZ * IN_DIM * 2 + (size_t)B_SZ * N_RES * 2 + (size_t)B_SZ * 12288;

  int Tc = T_STEPS;
  while (Tc > 1 && fixed + (size_t)Tc * per > ws_size) Tc >>= 1;

  short*          A2  = (short*)(ws + fixed);
  _Float16*       ipb = (_Float16*)(ws + fixed + (size_t)Tc * B_SZ * IN_DIM * 2);
  unsigned char*  gtb = (unsigned char*)(ws + fixed + (size_t)Tc * B_SZ * IN_DIM * 2
                                         + (size_t)Tc * B_SZ * N_RES * 2);

  k_zero_pad<<<T_STEPS * B_SZ, 128, 0, stream>>>(out);
  k_init_s8<<<(B_SZ * N_RES) / 1024, 256, 0, stream>>>(state0, s8_0);
  k_wres_t<<<dim3(64, 64), 256, 0, stream>>>(W_res, WresBT8);
  k_build_b2<<<16384, 256, 0, stream>>>(W_in, W_gate, B2);

  for (int t0 = 0; t0 < T_STEPS; t0 += Tc) {
    k_build_a2<<<Tc * B_SZ, 256, 0, stream>>>(x, A2, t0);
    int Mrows = Tc * B_SZ;
    int mtiles = (Mrows + 255) / 256;
    k_gemm_pre<<<mtiles * 64, 512, 0, stream>>>(A2, B2, ipb, gtb, Mrows);
    for (int tl = 0; tl < Tc; ++tl) {
      int t = t0 + tl;
      const unsigned char* Ar = (t & 1) ? s8_1 : s8_0;
      unsigned char*       Aw = (t & 1) ? s8_0 : s8_1;
      const float* prev = (t == 0) ? state0 : out + (size_t)(t - 1) * B_SZ * MAXD;
      k_step_gemm<<<256, 512, 0, stream>>>(Ar, WresBT8, part);
      k_step_red<<<512, 256, 0, stream>>>(
          part,
          ipb + (size_t)tl * B_SZ * N_RES,
          gtb + (size_t)tl * B_SZ * 12288,
          prev, Aw,
          out + (size_t)t * B_SZ * MAXD);
    }
  }
}